// Round 1
// baseline (313.518 us; speedup 1.0000x reference)
//
#include <hip/hip_runtime.h>

typedef unsigned short u16;
typedef unsigned int   u32;
typedef __attribute__((ext_vector_type(8))) short short8;
typedef __attribute__((ext_vector_type(4))) float f32x4;

#define AS1 __attribute__((address_space(1)))
#define AS3 __attribute__((address_space(3)))

#define NSEQ  1025
#define BB    8
#define DD    768
#define HH    12
#define MROWS 8200   // B*N valid rows
#define MPAD  8320   // padded to 65*128
#define KPAD  1088   // keys padded to 17*64

__device__ __forceinline__ void gl2lds16(const void* g, void* l) {
  __builtin_amdgcn_global_load_lds((const AS1 u32*)g, (AS3 u32*)l, 16, 0, 0);
}
__device__ __forceinline__ u16 f2bf(float f) {
  u32 u = __float_as_uint(f);
  return (u16)((u + 0x7FFFu + ((u >> 16) & 1u)) >> 16);
}
__device__ __forceinline__ float bf2f(u16 u) { return __uint_as_float(((u32)u) << 16); }

// ---------------------------------------------------------------------------
// prep: cast x -> xb bf16 [MPAD x 768] (transposed (n,b)->(b,n), pad rows = 0),
//       w_qkv rows [768,2304) -> wkv bf16 [1536 x 768],
//       w_proj -> wpj bf16 [768 x 768]
// ---------------------------------------------------------------------------
__global__ __launch_bounds__(256) void prep(const float* __restrict__ x,
                                            const float* __restrict__ wqkv,
                                            const float* __restrict__ wproj,
                                            u16* __restrict__ xb,
                                            u16* __restrict__ wkv,
                                            u16* __restrict__ wpj) {
  const int XB_G  = MPAD * 192;   // float4 groups
  const int WKV_G = 1536 * 192;
  const int WPJ_G = 768 * 192;
  int g = blockIdx.x * 256 + threadIdx.x;
  float4 v;
  u16* dst;
  size_t di;
  if (g < XB_G) {
    int m = g / 192, e4 = g - m * 192;
    if (m < MROWS) {
      int bb = m / NSEQ, ns = m - bb * NSEQ;
      v = ((const float4*)x)[(size_t)(ns * BB + bb) * 192 + e4];
    } else {
      v.x = v.y = v.z = v.w = 0.f;
    }
    dst = xb; di = (size_t)g;
  } else if (g < XB_G + WKV_G) {
    int r = g - XB_G;
    v = ((const float4*)wqkv)[(size_t)147456 + r];  // skip first 768 rows
    dst = wkv; di = (size_t)r;
  } else if (g < XB_G + WKV_G + WPJ_G) {
    int r = g - XB_G - WKV_G;
    v = ((const float4*)wproj)[r];
    dst = wpj; di = (size_t)r;
  } else {
    return;
  }
  uint2 o;
  o.x = (u32)f2bf(v.x) | ((u32)f2bf(v.y) << 16);
  o.y = (u32)f2bf(v.z) | ((u32)f2bf(v.w) << 16);
  ((uint2*)dst)[di] = o;
}

// ---------------------------------------------------------------------------
// gemm_bt: C[m,n] = sum_k A[m,k]*W[n,k]; 128x128 tile, BK=32, m97-style.
// MODE 0: store bf16 to Cbf (ldc cols).  MODE 1: +bias, fp32 scatter to [N,B,D].
// ---------------------------------------------------------------------------
template <int MODE>
__global__ __launch_bounds__(256) void gemm_bt(const u16* __restrict__ A,
                                               const u16* __restrict__ W,
                                               u16* __restrict__ Cbf,
                                               float* __restrict__ Cf,
                                               const float* __restrict__ bias,
                                               int ldc) {
  __shared__ u16 sA[128 * 32];
  __shared__ u16 sW[128 * 32];
  const int tid = threadIdx.x;
  const int w = tid >> 6, lane = tid & 63;
  const int m0 = blockIdx.y << 7, n0 = blockIdx.x << 7;
  const int wm = w & 1, wn = w >> 1;
  const int lc = lane & 15, lr = lane >> 4;

  f32x4 zero4 = {0.f, 0.f, 0.f, 0.f};
  f32x4 acc[4][4];
#pragma unroll
  for (int i = 0; i < 4; ++i)
#pragma unroll
    for (int j = 0; j < 4; ++j) acc[i][j] = zero4;

  const int lin0 = (w << 11) + (lane << 4);  // bytes
  const int r0 = lin0 >> 6;
  const int koff = (lane & 3) << 3;
  const u16* gA0 = A + (size_t)(m0 + r0) * DD + koff;
  const u16* gA1 = gA0 + (size_t)16 * DD;
  const u16* gW0 = W + (size_t)(n0 + r0) * DD + koff;
  const u16* gW1 = gW0 + (size_t)16 * DD;
  char* lA0 = (char*)sA + lin0;
  char* lW0 = (char*)sW + lin0;

#pragma unroll 1
  for (int kt = 0; kt < 24; ++kt) {
    __syncthreads();
    gl2lds16(gA0 + kt * 32, lA0);
    gl2lds16(gA1 + kt * 32, lA0 + 1024);
    gl2lds16(gW0 + kt * 32, lW0);
    gl2lds16(gW1 + kt * 32, lW0 + 1024);
    __syncthreads();
    short8 af[4], wf[4];
#pragma unroll
    for (int mt = 0; mt < 4; ++mt)
      af[mt] = *(const short8*)((char*)sA + ((wm << 6) + (mt << 4) + lc) * 64 + (lr << 4));
#pragma unroll
    for (int nt = 0; nt < 4; ++nt)
      wf[nt] = *(const short8*)((char*)sW + ((wn << 6) + (nt << 4) + lc) * 64 + (lr << 4));
#pragma unroll
    for (int mt = 0; mt < 4; ++mt)
#pragma unroll
      for (int nt = 0; nt < 4; ++nt)
        acc[mt][nt] = __builtin_amdgcn_mfma_f32_16x16x32_bf16(af[mt], wf[nt], acc[mt][nt], 0, 0, 0);
  }

  if (MODE == 0) {
#pragma unroll
    for (int mt = 0; mt < 4; ++mt)
#pragma unroll
      for (int r = 0; r < 4; ++r) {
        int m = m0 + (wm << 6) + (mt << 4) + (lr << 2) + r;
        if (m < MROWS) {
          size_t base = (size_t)m * ldc + n0 + (wn << 6) + lc;
#pragma unroll
          for (int nt = 0; nt < 4; ++nt) Cbf[base + (nt << 4)] = f2bf(acc[mt][nt][r]);
        }
      }
  } else {
    float b4[4];
#pragma unroll
    for (int nt = 0; nt < 4; ++nt) b4[nt] = bias[n0 + (wn << 6) + (nt << 4) + lc];
#pragma unroll
    for (int mt = 0; mt < 4; ++mt)
#pragma unroll
      for (int r = 0; r < 4; ++r) {
        int m = m0 + (wm << 6) + (mt << 4) + (lr << 2) + r;
        if (m < MROWS) {
          int bb = m / NSEQ;
          int ns = m - bb * NSEQ;
          float* o = Cf + (size_t)ns * (BB * DD) + bb * DD + n0 + (wn << 6) + lc;
#pragma unroll
          for (int nt = 0; nt < 4; ++nt) o[nt << 4] = acc[mt][nt][r] + b4[nt];
        }
      }
  }
}

// ---------------------------------------------------------------------------
// q0: fp32 q row 0 per batch: q0[b,d'] = sum_e x[0,b,e]*w_qkv[d',e], d' in [0,768)
// ---------------------------------------------------------------------------
__global__ __launch_bounds__(256) void q0_kernel(const float* __restrict__ x,
                                                 const float* __restrict__ wq,
                                                 float* __restrict__ q0) {
  __shared__ float red[256];
  int bid = blockIdx.x;
  int b = bid / HH, c = bid - b * HH;
  int tid = threadIdx.x;
  int dp = (c << 6) + (tid >> 2), part = tid & 3;
  const float4* x4 = (const float4*)(x + (size_t)b * DD + part * 192);
  const float4* w4 = (const float4*)(wq + (size_t)dp * DD + part * 192);
  float acc = 0.f;
#pragma unroll 4
  for (int e = 0; e < 48; ++e) {
    float4 a = x4[e], w = w4[e];
    acc += a.x * w.x + a.y * w.y + a.z * w.z + a.w * w.w;
  }
  red[tid] = acc;
  __syncthreads();
  if (part == 0) q0[b * DD + dp] = red[tid] + red[tid + 1] + red[tid + 2] + red[tid + 3];
}

// ---------------------------------------------------------------------------
// transpose_v: vT[bh][d][key] (KPAD cols, zero-padded) + inv-norms (1/max(||v||,eps))
// ---------------------------------------------------------------------------
__global__ __launch_bounds__(256) void transpose_v(const u16* __restrict__ kv,
                                                   u16* __restrict__ vT,
                                                   float* __restrict__ invn) {
  __shared__ u16 tile[64][72];
  __shared__ float red[256];
  int bid = blockIdx.x;
  int kc = bid % 17;
  int t2 = bid / 17;
  int h = t2 % HH, b = t2 / HH;
  int tid = threadIdx.x;
  int kl = tid >> 2, dc = (tid & 3) << 4;
  int key = kc * 64 + kl;
  u32 vals[8];
  if (key < NSEQ) {
    const u32* g = (const u32*)(kv + ((size_t)b * NSEQ + key) * 1536 + DD + h * 64 + dc);
#pragma unroll
    for (int i = 0; i < 8; ++i) vals[i] = g[i];
  } else {
#pragma unroll
    for (int i = 0; i < 8; ++i) vals[i] = 0;
  }
  float part = 0.f;
#pragma unroll
  for (int i = 0; i < 8; ++i) {
    float a = bf2f((u16)(vals[i] & 0xFFFF));
    float c = bf2f((u16)(vals[i] >> 16));
    part += a * a + c * c;
    ((u32*)&tile[kl][dc])[i] = vals[i];
  }
  red[tid] = part;
  __syncthreads();
  if ((tid & 3) == 0) {
    float s = red[tid] + red[tid + 1] + red[tid + 2] + red[tid + 3];
    float iv = (key < NSEQ) ? 1.0f / fmaxf(sqrtf(s), 1e-6f) : 1.0f;
    invn[(size_t)(b * HH + h) * KPAD + key] = iv;
  }
  int dl = tid >> 2, ks = (tid & 3) << 4;
  u32 ov[8];
#pragma unroll
  for (int i = 0; i < 8; ++i)
    ov[i] = (u32)tile[ks + 2 * i][dl] | ((u32)tile[ks + 2 * i + 1][dl] << 16);
  u16* o = vT + (size_t)(b * HH + h) * 64 * KPAD + (size_t)dl * KPAD + kc * 64 + ks;
#pragma unroll
  for (int i = 0; i < 8; ++i) ((u32*)o)[i] = ov[i];
}

// ---------------------------------------------------------------------------
// row0_attn: fp32 scores softmax(q0·k*0.125) @ v  -> attn row 0 per (b,h)
// ---------------------------------------------------------------------------
__global__ __launch_bounds__(256) void row0_attn(const float* __restrict__ q0,
                                                 const u16* __restrict__ kv,
                                                 u16* __restrict__ attn) {
  __shared__ float sq[64];
  __shared__ float sc[NSEQ];
  __shared__ float red[256];
  int bid = blockIdx.x;
  int b = bid / HH, h = bid - b * HH;
  int tid = threadIdx.x;
  if (tid < 64) sq[tid] = q0[b * DD + h * 64 + tid];
  __syncthreads();
  float mx = -1e30f;
  for (int n = tid; n < NSEQ; n += 256) {
    const u32* kr = (const u32*)(kv + ((size_t)b * NSEQ + n) * 1536 + h * 64);
    float s = 0.f;
#pragma unroll
    for (int i = 0; i < 32; ++i) {
      u32 u = kr[i];
      s += bf2f((u16)(u & 0xFFFF)) * sq[2 * i] + bf2f((u16)(u >> 16)) * sq[2 * i + 1];
    }
    s *= 0.125f;
    sc[n] = s;
    mx = fmaxf(mx, s);
  }
  red[tid] = mx;
  __syncthreads();
  for (int st = 128; st > 0; st >>= 1) {
    if (tid < st) red[tid] = fmaxf(red[tid], red[tid + st]);
    __syncthreads();
  }
  mx = red[0];
  __syncthreads();
  float ds = 0.f;
  for (int n = tid; n < NSEQ; n += 256) {
    float p = __expf(sc[n] - mx);
    sc[n] = p;
    ds += p;
  }
  red[tid] = ds;
  __syncthreads();
  for (int st = 128; st > 0; st >>= 1) {
    if (tid < st) red[tid] += red[tid + st];
    __syncthreads();
  }
  float den = red[0];
  __syncthreads();
  int d = tid & 63, pp = tid >> 6;
  float acc = 0.f;
  for (int n = pp; n < NSEQ; n += 4)
    acc += sc[n] * bf2f(kv[((size_t)b * NSEQ + n) * 1536 + DD + h * 64 + d]);
  red[tid] = acc;
  __syncthreads();
  if (tid < 64) {
    float o = (red[tid] + red[tid + 64] + red[tid + 128] + red[tid + 192]) / den;
    attn[(size_t)b * NSEQ * DD + h * 64 + tid] = f2bf(o);
  }
}

// ---------------------------------------------------------------------------
// vv_attn: per (b,h,128-q-tile): S^T = K·Q^T (MFMA), p = exp2(s*0.125*log2e*iq*ik),
// P->LDS (b64, [q][k]), out += P@V^T (MFMA), den += P@ones (MFMA). No max-rescale
// needed: |s| <= 0.125.
// ---------------------------------------------------------------------------
__global__ __launch_bounds__(256) void vv_attn(const u16* __restrict__ kv,
                                               const u16* __restrict__ vT,
                                               const float* __restrict__ invn,
                                               u16* __restrict__ attn) {
  __shared__ u16 sQ[2 * 128 * 32];  // [d-half][qrow 128][k 32]
  __shared__ u16 sK[2 * 64 * 32];   // [d-half][keyrow 64][k 32]
  __shared__ u16 sV[2 * 64 * 32];   // [key-half][d 64][k 32]  (from vT)
  __shared__ u16 sP[128 * 72];      // [q][key 64 (+8 pad)], 144B row stride
  __shared__ float sIK[64];

  const int tid = threadIdx.x, w = tid >> 6, lane = tid & 63;
  const int lc = lane & 15, lr = lane >> 4;
  const int mb = blockIdx.x, h = blockIdx.y, b = blockIdx.z;
  const int bh = b * HH + h;
  const int m0 = mb << 7;
  const size_t vbase = (size_t)b * NSEQ * 1536 + DD + h * 64;
  const size_t tbase = (size_t)bh * 64 * KPAD;
  const float* invbh = invn + (size_t)bh * KPAD;

  // stage Q tile (rows 1+m0 .. 1+m0+127), once
#pragma unroll
  for (int j = 0; j < 4; ++j) {
    int lin = (w << 12) + (j << 10) + (lane << 4);
    int hf = lin >> 13, rem = lin & 8191;
    int r = rem >> 6, kof = (lane & 3) << 3;
    gl2lds16(kv + vbase + (size_t)(1 + m0 + r) * 1536 + hf * 32 + kof, (char*)sQ + lin);
  }

  float fq[2];
#pragma unroll
  for (int nt = 0; nt < 2; ++nt)
    fq[nt] = 0.1803368801111204f * invbh[1 + m0 + (w << 5) + (nt << 4) + lc];  // 0.125*log2(e)*inv_q

  f32x4 zero4 = {0.f, 0.f, 0.f, 0.f};
  f32x4 oacc[2][4];
  f32x4 dacc[2];
#pragma unroll
  for (int i = 0; i < 2; ++i) {
    dacc[i] = zero4;
#pragma unroll
    for (int j = 0; j < 4; ++j) oacc[i][j] = zero4;
  }
  short8 ones;
#pragma unroll
  for (int i = 0; i < 8; ++i) ones[i] = (short)0x3F80;  // bf16 1.0

#pragma unroll 1
  for (int kt = 0; kt < 17; ++kt) {
    __syncthreads();
#pragma unroll
    for (int j = 0; j < 2; ++j) {
      int lin = (w << 11) + (j << 10) + (lane << 4);
      int hf = lin >> 12, rem = lin & 4095;
      int r = rem >> 6, kof = (lane & 3) << 3;
      gl2lds16(kv + vbase + (size_t)(kt * 64 + r) * 1536 + hf * 32 + kof, (char*)sK + lin);
      gl2lds16(vT + tbase + (size_t)r * KPAD + kt * 64 + hf * 32 + kof, (char*)sV + lin);
    }
    if (tid < 64) sIK[tid] = invbh[kt * 64 + tid];
    __syncthreads();

    // S^T = K_tile @ Q^T  (C rows = keys, cols = queries)
    f32x4 sacc[4][2];
#pragma unroll
    for (int mt = 0; mt < 4; ++mt)
#pragma unroll
      for (int nt = 0; nt < 2; ++nt) sacc[mt][nt] = zero4;
#pragma unroll
    for (int kk = 0; kk < 2; ++kk) {
      short8 ak[4], bq[2];
#pragma unroll
      for (int mt = 0; mt < 4; ++mt)
        ak[mt] = *(const short8*)((char*)sK + (kk << 12) + ((mt << 4) + lc) * 64 + (lr << 4));
#pragma unroll
      for (int nt = 0; nt < 2; ++nt)
        bq[nt] = *(const short8*)((char*)sQ + (kk << 13) + ((w << 5) + (nt << 4) + lc) * 64 + (lr << 4));
#pragma unroll
      for (int mt = 0; mt < 4; ++mt)
#pragma unroll
        for (int nt = 0; nt < 2; ++nt)
          sacc[mt][nt] = __builtin_amdgcn_mfma_f32_16x16x32_bf16(ak[mt], bq[nt], sacc[mt][nt], 0, 0, 0);
    }

    // p = exp2(s * f), masked; write 4 k-consecutive bf16 per lane (b64) into sP[q][k]
#pragma unroll
    for (int mt = 0; mt < 4; ++mt) {
      int kl0 = (mt << 4) + (lr << 2);
      int keyg = kt * 64 + kl0;
      float g0 = sIK[kl0], g1 = sIK[kl0 + 1], g2 = sIK[kl0 + 2], g3 = sIK[kl0 + 3];
      bool m0v = (keyg) <= 1024, m1v = (keyg + 1) <= 1024, m2v = (keyg + 2) <= 1024, m3v = (keyg + 3) <= 1024;
#pragma unroll
      for (int nt = 0; nt < 2; ++nt) {
        int q = (w << 5) + (nt << 4) + lc;
        float p0 = m0v ? exp2f(sacc[mt][nt][0] * (fq[nt] * g0)) : 0.f;
        float p1 = m1v ? exp2f(sacc[mt][nt][1] * (fq[nt] * g1)) : 0.f;
        float p2 = m2v ? exp2f(sacc[mt][nt][2] * (fq[nt] * g2)) : 0.f;
        float p3 = m3v ? exp2f(sacc[mt][nt][3] * (fq[nt] * g3)) : 0.f;
        uint2 pv;
        pv.x = (u32)f2bf(p0) | ((u32)f2bf(p1) << 16);
        pv.y = (u32)f2bf(p2) | ((u32)f2bf(p3) << 16);
        *(uint2*)((char*)sP + q * 144 + (kl0 << 1)) = pv;
      }
    }

    // out += P @ V^T ; den += P @ ones   (sP rows are wave-private: no barrier)
#pragma unroll
    for (int kk = 0; kk < 2; ++kk) {
      short8 ap[2], bv[4];
#pragma unroll
      for (int mt = 0; mt < 2; ++mt)
        ap[mt] = *(const short8*)((char*)sP + ((w << 5) + (mt << 4) + lc) * 144 + (kk << 6) + (lr << 4));
#pragma unroll
      for (int nt = 0; nt < 4; ++nt)
        bv[nt] = *(const short8*)((char*)sV + (kk << 12) + ((nt << 4) + lc) * 64 + (lr << 4));
#pragma unroll
      for (int mt = 0; mt < 2; ++mt) {
#pragma unroll
        for (int nt = 0; nt < 4; ++nt)
          oacc[mt][nt] = __builtin_amdgcn_mfma_f32_16x16x32_bf16(ap[mt], bv[nt], oacc[mt][nt], 0, 0, 0);
        dacc[mt] = __builtin_amdgcn_mfma_f32_16x16x32_bf16(ap[mt], ones, dacc[mt], 0, 0, 0);
      }
    }
  }

  // epilogue: out/den -> attn rows 1+m0+q
#pragma unroll
  for (int mt = 0; mt < 2; ++mt) {
#pragma unroll
    for (int r = 0; r < 4; ++r) {
      int q = (w << 5) + (mt << 4) + (lr << 2) + r;
      int nseq = 1 + m0 + q;
      float rdn = 1.0f / dacc[mt][r];
      size_t obase = ((size_t)b * NSEQ + nseq) * DD + h * 64 + lc;
#pragma unroll
      for (int nt = 0; nt < 4; ++nt) attn[obase + (nt << 4)] = f2bf(oacc[mt][nt][r] * rdn);
    }
  }
}

// ---------------------------------------------------------------------------
// launcher
// ---------------------------------------------------------------------------
extern "C" void kernel_launch(void* const* d_in, const int* in_sizes, int n_in,
                              void* d_out, int out_size, void* d_ws, size_t ws_size,
                              hipStream_t stream) {
  const float* x      = (const float*)d_in[0];
  const float* w_qkv  = (const float*)d_in[1];
  const float* w_proj = (const float*)d_in[2];
  const float* b_proj = (const float*)d_in[3];
  float* out = (float*)d_out;
  char* ws = (char*)d_ws;

  // workspace layout (bytes). xb region is reused by vT after the qkv GEMM.
  u16*   xb   = (u16*)(ws + 0);            // 8320*768*2   = 12,779,520
  u16*   vT   = (u16*)(ws + 0);            // 96*64*1088*2 = 13,369,344 (aliases xb+wkv-head)
  u16*   wkv  = (u16*)(ws + 13369344);     // 1536*768*2   =  2,359,296
  u16*   wpj  = (u16*)(ws + 15728640);     // 768*768*2    =  1,179,648
  u16*   kvb  = (u16*)(ws + 16908288);     // 8320*1536*2  = 25,559,040
  float* q0   = (float*)(ws + 42467328);   // 8*768*4      =     24,576
  float* invb = (float*)(ws + 42491904);   // 96*1088*4    =    417,792
  u16*   attn = (u16*)(ws + 42909696);     // 8320*768*2   = 12,779,520
  // total: 55,689,216 bytes

  prep<<<7968, 256, 0, stream>>>(x, w_qkv, w_proj, xb, wkv, wpj);
  gemm_bt<0><<<dim3(12, 65), 256, 0, stream>>>(xb, wkv, kvb, nullptr, nullptr, 1536);
  q0_kernel<<<96, 256, 0, stream>>>(x, w_qkv, q0);
  transpose_v<<<1632, 256, 0, stream>>>(kvb, vT, invb);     // overwrites xb/wkv region
  row0_attn<<<96, 256, 0, stream>>>(q0, kvb, attn);
  vv_attn<<<dim3(8, 12, 8), 256, 0, stream>>>(kvb, vT, invb, attn);
  gemm_bt<1><<<dim3(6, 65), 256, 0, stream>>>(attn, wpj, nullptr, out, b_proj, 768);
}

// Round 2
// 293.526 us; speedup vs baseline: 1.0681x; 1.0681x over previous
//
#include <hip/hip_runtime.h>

typedef unsigned short u16;
typedef unsigned int   u32;
typedef __attribute__((ext_vector_type(8))) short short8;
typedef __attribute__((ext_vector_type(4))) float f32x4;

#define AS1 __attribute__((address_space(1)))
#define AS3 __attribute__((address_space(3)))

#define NSEQ  1025
#define BB    8
#define DD    768
#define HH    12
#define MROWS 8200   // B*N valid rows
#define MPAD  8320   // padded to 65*128
#define KPAD  1088   // keys padded to 17*64

__device__ __forceinline__ void gl2lds16(const void* g, void* l) {
  __builtin_amdgcn_global_load_lds((const AS1 u32*)g, (AS3 u32*)l, 16, 0, 0);
}
__device__ __forceinline__ u16 f2bf(float f) {
  u32 u = __float_as_uint(f);
  return (u16)((u + 0x7FFFu + ((u >> 16) & 1u)) >> 16);
}
__device__ __forceinline__ float bf2f(u16 u) { return __uint_as_float(((u32)u) << 16); }

// ---------------------------------------------------------------------------
// prep: cast x -> xb bf16 [MPAD x 768] (transposed (n,b)->(b,n), pad rows = 0),
//       w_qkv rows [768,2304) -> wkv bf16 [1536 x 768],
//       w_proj -> wpj bf16 [768 x 768]
// ---------------------------------------------------------------------------
__global__ __launch_bounds__(256) void prep(const float* __restrict__ x,
                                            const float* __restrict__ wqkv,
                                            const float* __restrict__ wproj,
                                            u16* __restrict__ xb,
                                            u16* __restrict__ wkv,
                                            u16* __restrict__ wpj) {
  const int XB_G  = MPAD * 192;   // float4 groups
  const int WKV_G = 1536 * 192;
  const int WPJ_G = 768 * 192;
  int g = blockIdx.x * 256 + threadIdx.x;
  float4 v;
  u16* dst;
  size_t di;
  if (g < XB_G) {
    int m = g / 192, e4 = g - m * 192;
    if (m < MROWS) {
      int bb = m / NSEQ, ns = m - bb * NSEQ;
      v = ((const float4*)x)[(size_t)(ns * BB + bb) * 192 + e4];
    } else {
      v.x = v.y = v.z = v.w = 0.f;
    }
    dst = xb; di = (size_t)g;
  } else if (g < XB_G + WKV_G) {
    int r = g - XB_G;
    v = ((const float4*)wqkv)[(size_t)147456 + r];  // skip first 768 rows
    dst = wkv; di = (size_t)r;
  } else if (g < XB_G + WKV_G + WPJ_G) {
    int r = g - XB_G - WKV_G;
    v = ((const float4*)wproj)[r];
    dst = wpj; di = (size_t)r;
  } else {
    return;
  }
  uint2 o;
  o.x = (u32)f2bf(v.x) | ((u32)f2bf(v.y) << 16);
  o.y = (u32)f2bf(v.z) | ((u32)f2bf(v.w) << 16);
  ((uint2*)dst)[di] = o;
}

// ---------------------------------------------------------------------------
// gemm_bt: C[m,n] = sum_k A[m,k]*W[n,k]; 128x128 tile, BK=32, m97-style.
// MODE 0: store bf16 to Cbf (ldc cols).  MODE 1: +bias, fp32 scatter to [N,B,D].
// ---------------------------------------------------------------------------
template <int MODE>
__global__ __launch_bounds__(256) void gemm_bt(const u16* __restrict__ A,
                                               const u16* __restrict__ W,
                                               u16* __restrict__ Cbf,
                                               float* __restrict__ Cf,
                                               const float* __restrict__ bias,
                                               int ldc) {
  __shared__ u16 sA[128 * 32];
  __shared__ u16 sW[128 * 32];
  const int tid = threadIdx.x;
  const int w = tid >> 6, lane = tid & 63;
  const int m0 = blockIdx.y << 7, n0 = blockIdx.x << 7;
  const int wm = w & 1, wn = w >> 1;
  const int lc = lane & 15, lr = lane >> 4;

  f32x4 zero4 = {0.f, 0.f, 0.f, 0.f};
  f32x4 acc[4][4];
#pragma unroll
  for (int i = 0; i < 4; ++i)
#pragma unroll
    for (int j = 0; j < 4; ++j) acc[i][j] = zero4;

  const int lin0 = (w << 11) + (lane << 4);  // bytes
  const int r0 = lin0 >> 6;
  const int koff = (lane & 3) << 3;
  const u16* gA0 = A + (size_t)(m0 + r0) * DD + koff;
  const u16* gA1 = gA0 + (size_t)16 * DD;
  const u16* gW0 = W + (size_t)(n0 + r0) * DD + koff;
  const u16* gW1 = gW0 + (size_t)16 * DD;
  char* lA0 = (char*)sA + lin0;
  char* lW0 = (char*)sW + lin0;

#pragma unroll 1
  for (int kt = 0; kt < 24; ++kt) {
    __syncthreads();
    gl2lds16(gA0 + kt * 32, lA0);
    gl2lds16(gA1 + kt * 32, lA0 + 1024);
    gl2lds16(gW0 + kt * 32, lW0);
    gl2lds16(gW1 + kt * 32, lW0 + 1024);
    __syncthreads();
    short8 af[4], wf[4];
#pragma unroll
    for (int mt = 0; mt < 4; ++mt)
      af[mt] = *(const short8*)((char*)sA + ((wm << 6) + (mt << 4) + lc) * 64 + (lr << 4));
#pragma unroll
    for (int nt = 0; nt < 4; ++nt)
      wf[nt] = *(const short8*)((char*)sW + ((wn << 6) + (nt << 4) + lc) * 64 + (lr << 4));
#pragma unroll
    for (int mt = 0; mt < 4; ++mt)
#pragma unroll
      for (int nt = 0; nt < 4; ++nt)
        acc[mt][nt] = __builtin_amdgcn_mfma_f32_16x16x32_bf16(af[mt], wf[nt], acc[mt][nt], 0, 0, 0);
  }

  if (MODE == 0) {
#pragma unroll
    for (int mt = 0; mt < 4; ++mt)
#pragma unroll
      for (int r = 0; r < 4; ++r) {
        int m = m0 + (wm << 6) + (mt << 4) + (lr << 2) + r;
        if (m < MROWS) {
          size_t base = (size_t)m * ldc + n0 + (wn << 6) + lc;
#pragma unroll
          for (int nt = 0; nt < 4; ++nt) Cbf[base + (nt << 4)] = f2bf(acc[mt][nt][r]);
        }
      }
  } else {
    float b4[4];
#pragma unroll
    for (int nt = 0; nt < 4; ++nt) b4[nt] = bias[n0 + (wn << 6) + (nt << 4) + lc];
#pragma unroll
    for (int mt = 0; mt < 4; ++mt)
#pragma unroll
      for (int r = 0; r < 4; ++r) {
        int m = m0 + (wm << 6) + (mt << 4) + (lr << 2) + r;
        if (m < MROWS) {
          int bb = m / NSEQ;
          int ns = m - bb * NSEQ;
          float* o = Cf + (size_t)ns * (BB * DD) + bb * DD + n0 + (wn << 6) + lc;
#pragma unroll
          for (int nt = 0; nt < 4; ++nt) o[nt << 4] = acc[mt][nt][r] + b4[nt];
        }
      }
  }
}

// ---------------------------------------------------------------------------
// q0: fp32 q row 0 per batch: q0[b,d'] = sum_e x[0,b,e]*w_qkv[d',e], d' in [0,768)
// ---------------------------------------------------------------------------
__global__ __launch_bounds__(256) void q0_kernel(const float* __restrict__ x,
                                                 const float* __restrict__ wq,
                                                 float* __restrict__ q0) {
  __shared__ float red[256];
  int bid = blockIdx.x;
  int b = bid / HH, c = bid - b * HH;
  int tid = threadIdx.x;
  int dp = (c << 6) + (tid >> 2), part = tid & 3;
  const float4* x4 = (const float4*)(x + (size_t)b * DD + part * 192);
  const float4* w4 = (const float4*)(wq + (size_t)dp * DD + part * 192);
  float acc = 0.f;
#pragma unroll 4
  for (int e = 0; e < 48; ++e) {
    float4 a = x4[e], w = w4[e];
    acc += a.x * w.x + a.y * w.y + a.z * w.z + a.w * w.w;
  }
  red[tid] = acc;
  __syncthreads();
  if (part == 0) q0[b * DD + dp] = red[tid] + red[tid + 1] + red[tid + 2] + red[tid + 3];
}

// ---------------------------------------------------------------------------
// transpose_v: vT[bh][d][key] raw (KPAD cols, zero-padded) AND
//              vn[bh][key][64] = v/max(||v||,eps) bf16 (zero pad rows)
// ---------------------------------------------------------------------------
__global__ __launch_bounds__(256) void transpose_v(const u16* __restrict__ kv,
                                                   u16* __restrict__ vT,
                                                   u16* __restrict__ vn) {
  __shared__ u16 tile[64][72];
  __shared__ float red[256];
  __shared__ float sInv[64];
  int bid = blockIdx.x;
  int kc = bid % 17;
  int t2 = bid / 17;
  int h = t2 % HH, b = t2 / HH;
  int tid = threadIdx.x;
  int kl = tid >> 2, dc = (tid & 3) << 4;
  int key = kc * 64 + kl;
  u32 vals[8];
  if (key < NSEQ) {
    const u32* g = (const u32*)(kv + ((size_t)b * NSEQ + key) * 1536 + DD + h * 64 + dc);
#pragma unroll
    for (int i = 0; i < 8; ++i) vals[i] = g[i];
  } else {
#pragma unroll
    for (int i = 0; i < 8; ++i) vals[i] = 0;
  }
  float part = 0.f;
#pragma unroll
  for (int i = 0; i < 8; ++i) {
    float a = bf2f((u16)(vals[i] & 0xFFFF));
    float c = bf2f((u16)(vals[i] >> 16));
    part += a * a + c * c;
    ((u32*)&tile[kl][dc])[i] = vals[i];
  }
  red[tid] = part;
  __syncthreads();
  if ((tid & 3) == 0) {
    float s = red[tid] + red[tid + 1] + red[tid + 2] + red[tid + 3];
    sInv[kl] = (key < NSEQ) ? 1.0f / fmaxf(sqrtf(s), 1e-6f) : 0.0f;
  }
  __syncthreads();
  // normalized bf16 rows -> vn
  float iv = sInv[kl];
  u32 ovn[8];
#pragma unroll
  for (int i = 0; i < 8; ++i) {
    float a = bf2f((u16)(vals[i] & 0xFFFF)) * iv;
    float c = bf2f((u16)(vals[i] >> 16)) * iv;
    ovn[i] = (u32)f2bf(a) | ((u32)f2bf(c) << 16);
  }
  u32* on = (u32*)(vn + ((size_t)(b * HH + h) * KPAD + key) * 64 + dc);
#pragma unroll
  for (int i = 0; i < 8; ++i) on[i] = ovn[i];
  // raw transpose -> vT
  int dl = tid >> 2, ks = (tid & 3) << 4;
  u32 ov[8];
#pragma unroll
  for (int i = 0; i < 8; ++i)
    ov[i] = (u32)tile[ks + 2 * i][dl] | ((u32)tile[ks + 2 * i + 1][dl] << 16);
  u16* o = vT + (size_t)(b * HH + h) * 64 * KPAD + (size_t)dl * KPAD + kc * 64 + ks;
#pragma unroll
  for (int i = 0; i < 8; ++i) ((u32*)o)[i] = ov[i];
}

// ---------------------------------------------------------------------------
// row0_attn: fp32 scores softmax(q0·k*0.125) @ v  -> attn row 0 per (b,h)
// ---------------------------------------------------------------------------
__global__ __launch_bounds__(256) void row0_attn(const float* __restrict__ q0,
                                                 const u16* __restrict__ kv,
                                                 u16* __restrict__ attn) {
  __shared__ float sq[64];
  __shared__ float sc[NSEQ];
  __shared__ float red[256];
  int bid = blockIdx.x;
  int b = bid / HH, h = bid - b * HH;
  int tid = threadIdx.x;
  if (tid < 64) sq[tid] = q0[b * DD + h * 64 + tid];
  __syncthreads();
  float mx = -1e30f;
  for (int n = tid; n < NSEQ; n += 256) {
    const u32* kr = (const u32*)(kv + ((size_t)b * NSEQ + n) * 1536 + h * 64);
    float s = 0.f;
#pragma unroll
    for (int i = 0; i < 32; ++i) {
      u32 u = kr[i];
      s += bf2f((u16)(u & 0xFFFF)) * sq[2 * i] + bf2f((u16)(u >> 16)) * sq[2 * i + 1];
    }
    s *= 0.125f;
    sc[n] = s;
    mx = fmaxf(mx, s);
  }
  red[tid] = mx;
  __syncthreads();
  for (int st = 128; st > 0; st >>= 1) {
    if (tid < st) red[tid] = fmaxf(red[tid], red[tid + st]);
    __syncthreads();
  }
  mx = red[0];
  __syncthreads();
  float ds = 0.f;
  for (int n = tid; n < NSEQ; n += 256) {
    float p = __expf(sc[n] - mx);
    sc[n] = p;
    ds += p;
  }
  red[tid] = ds;
  __syncthreads();
  for (int st = 128; st > 0; st >>= 1) {
    if (tid < st) red[tid] += red[tid + st];
    __syncthreads();
  }
  float den = red[0];
  __syncthreads();
  int d = tid & 63, pp = tid >> 6;
  float acc = 0.f;
  for (int n = pp; n < NSEQ; n += 4)
    acc += sc[n] * bf2f(kv[((size_t)b * NSEQ + n) * 1536 + DD + h * 64 + d]);
  red[tid] = acc;
  __syncthreads();
  if (tid < 64) {
    float o = (red[tid] + red[tid + 64] + red[tid + 128] + red[tid + 192]) / den;
    attn[(size_t)b * NSEQ * DD + h * 64 + tid] = f2bf(o);
  }
}

// ---------------------------------------------------------------------------
// vv_attn: per (b,h,128-q-tile): S^T = Kn·Qn^T (MFMA, pre-normalized bf16),
// p = exp2(s*0.125*log2e)  (single literal mul + v_exp + v_perm pack),
// P->LDS (b64, [q][k]), out += P@V^T (MFMA), den += P@ones (MFMA).
// No online max needed: |s| <= 0.125. Pad keys masked only in last K-tile.
// ---------------------------------------------------------------------------
__global__ __launch_bounds__(256) void vv_attn(const u16* __restrict__ vn,
                                               const u16* __restrict__ vT,
                                               u16* __restrict__ attn) {
  __shared__ u16 sQ[2 * 128 * 32];  // [d-half][qrow 128][k 32]
  __shared__ u16 sK[2 * 64 * 32];   // [d-half][keyrow 64][k 32]
  __shared__ u16 sV[2 * 64 * 32];   // [key-half][d 64][k 32]  (from vT)
  __shared__ u16 sP[128 * 72];      // [q][key 64 (+8 pad)], 144B row stride

  const int tid = threadIdx.x, w = tid >> 6, lane = tid & 63;
  const int lc = lane & 15, lr = lane >> 4;
  const int mb = blockIdx.x, h = blockIdx.y, b = blockIdx.z;
  const int bh = b * HH + h;
  const int m0 = mb << 7;
  const char* nb = (const char*)(vn + (size_t)bh * KPAD * 64);  // 128B rows
  const char* tb = (const char*)(vT + (size_t)bh * 64 * KPAD);  // 2176B rows

  // stage Q tile (vn rows 1+m0 .. 1+m0+127), once; LDS layout [hf][row][32]
#pragma unroll
  for (int j = 0; j < 4; ++j) {
    int lin = (w << 12) + (j << 10) + (lane << 4);
    int hf = lin >> 13, r = (lin >> 6) & 127, off = lin & 63;
    gl2lds16(nb + (size_t)(1 + m0 + r) * 128 + hf * 64 + off, (char*)sQ + lin);
  }

  f32x4 zero4 = {0.f, 0.f, 0.f, 0.f};
  f32x4 oacc[2][4];
  f32x4 dacc[2];
#pragma unroll
  for (int i = 0; i < 2; ++i) {
    dacc[i] = zero4;
#pragma unroll
    for (int j = 0; j < 4; ++j) oacc[i][j] = zero4;
  }
  short8 ones;
#pragma unroll
  for (int i = 0; i < 8; ++i) ones[i] = (short)0x3F80;  // bf16 1.0

  const float CEXP = 0.1803368801111204f;  // 0.125 * log2(e)

#pragma unroll 1
  for (int kt = 0; kt < 17; ++kt) {
    __syncthreads();
#pragma unroll
    for (int j = 0; j < 2; ++j) {
      int lin = (w << 11) + (j << 10) + (lane << 4);
      int hf = lin >> 12, r = (lin >> 6) & 63, off = lin & 63;
      gl2lds16(nb + (size_t)(kt * 64 + r) * 128 + hf * 64 + off, (char*)sK + lin);
      gl2lds16(tb + (size_t)r * (KPAD * 2) + kt * 128 + hf * 64 + off, (char*)sV + lin);
    }
    __syncthreads();

    // S^T = Kn_tile @ Qn^T  (C rows = keys, cols = queries) — already cosine
    f32x4 sacc[4][2];
#pragma unroll
    for (int mt = 0; mt < 4; ++mt)
#pragma unroll
      for (int nt = 0; nt < 2; ++nt) sacc[mt][nt] = zero4;
#pragma unroll
    for (int kk = 0; kk < 2; ++kk) {
      short8 ak[4], bq[2];
#pragma unroll
      for (int mt = 0; mt < 4; ++mt)
        ak[mt] = *(const short8*)((char*)sK + (kk << 12) + ((mt << 4) + lc) * 64 + (lr << 4));
#pragma unroll
      for (int nt = 0; nt < 2; ++nt)
        bq[nt] = *(const short8*)((char*)sQ + (kk << 13) + ((w << 5) + (nt << 4) + lc) * 64 + (lr << 4));
#pragma unroll
      for (int mt = 0; mt < 4; ++mt)
#pragma unroll
        for (int nt = 0; nt < 2; ++nt)
          sacc[mt][nt] = __builtin_amdgcn_mfma_f32_16x16x32_bf16(ak[mt], bq[nt], sacc[mt][nt], 0, 0, 0);
    }

    // p = exp2(s * CEXP); round-half-up to bf16 via +0x8000 + v_perm pack;
    // 4 k-consecutive bf16 per lane (b64) into sP[q][k]
#pragma unroll
    for (int mt = 0; mt < 4; ++mt) {
      int kl0 = (mt << 4) + (lr << 2);
#pragma unroll
      for (int nt = 0; nt < 2; ++nt) {
        int q = (w << 5) + (nt << 4) + lc;
        u32 a0 = __float_as_uint(__builtin_amdgcn_exp2f(sacc[mt][nt][0] * CEXP)) + 0x8000u;
        u32 a1 = __float_as_uint(__builtin_amdgcn_exp2f(sacc[mt][nt][1] * CEXP)) + 0x8000u;
        u32 a2 = __float_as_uint(__builtin_amdgcn_exp2f(sacc[mt][nt][2] * CEXP)) + 0x8000u;
        u32 a3 = __float_as_uint(__builtin_amdgcn_exp2f(sacc[mt][nt][3] * CEXP)) + 0x8000u;
        uint2 pv;
        pv.x = __builtin_amdgcn_perm(a1, a0, 0x07060302u);
        pv.y = __builtin_amdgcn_perm(a3, a2, 0x07060302u);
        if (kt == 16) {  // keys 1024..1087: only key 1024 (kl0==0, elem 0) valid
          pv.x = (kl0 == 0) ? (pv.x & 0xFFFFu) : 0u;
          pv.y = 0u;
        }
        *(uint2*)((char*)sP + q * 144 + (kl0 << 1)) = pv;
      }
    }

    // out += P @ V^T ; den += P @ ones   (sP rows are wave-private: no barrier)
#pragma unroll
    for (int kk = 0; kk < 2; ++kk) {
      short8 ap[2], bv[4];
#pragma unroll
      for (int mt = 0; mt < 2; ++mt)
        ap[mt] = *(const short8*)((char*)sP + ((w << 5) + (mt << 4) + lc) * 144 + (kk << 6) + (lr << 4));
#pragma unroll
      for (int nt = 0; nt < 4; ++nt)
        bv[nt] = *(const short8*)((char*)sV + (kk << 12) + ((nt << 4) + lc) * 64 + (lr << 4));
#pragma unroll
      for (int mt = 0; mt < 2; ++mt) {
#pragma unroll
        for (int nt = 0; nt < 4; ++nt)
          oacc[mt][nt] = __builtin_amdgcn_mfma_f32_16x16x32_bf16(ap[mt], bv[nt], oacc[mt][nt], 0, 0, 0);
        dacc[mt] = __builtin_amdgcn_mfma_f32_16x16x32_bf16(ap[mt], ones, dacc[mt], 0, 0, 0);
      }
    }
  }

  // epilogue: out/den -> attn rows 1+m0+q
#pragma unroll
  for (int mt = 0; mt < 2; ++mt) {
#pragma unroll
    for (int r = 0; r < 4; ++r) {
      int q = (w << 5) + (mt << 4) + (lr << 2) + r;
      int nseq = 1 + m0 + q;
      float rdn = 1.0f / dacc[mt][r];
      size_t obase = ((size_t)b * NSEQ + nseq) * DD + h * 64 + lc;
#pragma unroll
      for (int nt = 0; nt < 4; ++nt) attn[obase + (nt << 4)] = f2bf(oacc[mt][nt][r] * rdn);
    }
  }
}

// ---------------------------------------------------------------------------
// launcher
// ---------------------------------------------------------------------------
extern "C" void kernel_launch(void* const* d_in, const int* in_sizes, int n_in,
                              void* d_out, int out_size, void* d_ws, size_t ws_size,
                              hipStream_t stream) {
  const float* x      = (const float*)d_in[0];
  const float* w_qkv  = (const float*)d_in[1];
  const float* w_proj = (const float*)d_in[2];
  const float* b_proj = (const float*)d_in[3];
  float* out = (float*)d_out;
  char* ws = (char*)d_ws;

  // workspace layout (bytes). xb region is reused by vT after the qkv GEMM.
  u16*   xb   = (u16*)(ws + 0);            // 8320*768*2   = 12,779,520
  u16*   vT   = (u16*)(ws + 0);            // 96*64*1088*2 = 13,369,344 (reuses xb, done)
  u16*   wkv  = (u16*)(ws + 13369344);     // 1536*768*2   =  2,359,296
  u16*   wpj  = (u16*)(ws + 15728640);     // 768*768*2    =  1,179,648
  u16*   kvb  = (u16*)(ws + 16908288);     // 8320*1536*2  = 25,559,040
  float* q0   = (float*)(ws + 42467328);   // 8*768*4      =     24,576
  u16*   attn = (u16*)(ws + 42491904);     // 8320*768*2   = 12,779,520
  u16*   vn   = (u16*)(ws + 55271424);     // 96*1088*64*2 = 13,369,344
  // total: 68,640,768 bytes

  prep<<<7968, 256, 0, stream>>>(x, w_qkv, w_proj, xb, wkv, wpj);
  gemm_bt<0><<<dim3(12, 65), 256, 0, stream>>>(xb, wkv, kvb, nullptr, nullptr, 1536);
  q0_kernel<<<96, 256, 0, stream>>>(x, w_qkv, q0);
  transpose_v<<<1632, 256, 0, stream>>>(kvb, vT, vn);     // overwrites xb/wkv region
  row0_attn<<<96, 256, 0, stream>>>(q0, kvb, attn);
  vv_attn<<<dim3(8, 12, 8), 256, 0, stream>>>(vn, vT, attn);
  gemm_bt<1><<<dim3(6, 65), 256, 0, stream>>>(attn, wpj, nullptr, out, b_proj, 768);
}

// Round 3
// 237.086 us; speedup vs baseline: 1.3224x; 1.2381x over previous
//
#include <hip/hip_runtime.h>

typedef unsigned short u16;
typedef unsigned int   u32;
typedef __attribute__((ext_vector_type(8))) short short8;
typedef __attribute__((ext_vector_type(4))) float f32x4;

#define AS1 __attribute__((address_space(1)))
#define AS3 __attribute__((address_space(3)))

#define NSEQ  1025
#define BB    8
#define DD    768
#define HH    12
#define MROWS 8200   // B*N valid rows
#define MPAD  8320   // padded to 65*128
#define KPAD  1088   // keys padded to 17*64

__device__ __forceinline__ void gl2lds16(const void* g, void* l) {
  __builtin_amdgcn_global_load_lds((const AS1 u32*)g, (AS3 u32*)l, 16, 0, 0);
}
__device__ __forceinline__ u16 f2bf(float f) {
  u32 u = __float_as_uint(f);
  return (u16)((u + 0x7FFFu + ((u >> 16) & 1u)) >> 16);
}
__device__ __forceinline__ float bf2f(u16 u) { return __uint_as_float(((u32)u) << 16); }

// ---------------------------------------------------------------------------
// prep: cast x -> xb bf16 [MPAD x 768] (transposed (n,b)->(b,n), pad rows = 0),
//       w_qkv rows [768,2304) -> wkv bf16 [1536 x 768],
//       w_proj -> wpj bf16 [768 x 768]
// ---------------------------------------------------------------------------
__global__ __launch_bounds__(256) void prep(const float* __restrict__ x,
                                            const float* __restrict__ wqkv,
                                            const float* __restrict__ wproj,
                                            u16* __restrict__ xb,
                                            u16* __restrict__ wkv,
                                            u16* __restrict__ wpj) {
  const int XB_G  = MPAD * 192;   // float4 groups
  const int WKV_G = 1536 * 192;
  const int WPJ_G = 768 * 192;
  int g = blockIdx.x * 256 + threadIdx.x;
  float4 v;
  u16* dst;
  size_t di;
  if (g < XB_G) {
    int m = g / 192, e4 = g - m * 192;
    if (m < MROWS) {
      int bb = m / NSEQ, ns = m - bb * NSEQ;
      v = ((const float4*)x)[(size_t)(ns * BB + bb) * 192 + e4];
    } else {
      v.x = v.y = v.z = v.w = 0.f;
    }
    dst = xb; di = (size_t)g;
  } else if (g < XB_G + WKV_G) {
    int r = g - XB_G;
    v = ((const float4*)wqkv)[(size_t)147456 + r];  // skip first 768 rows
    dst = wkv; di = (size_t)r;
  } else if (g < XB_G + WKV_G + WPJ_G) {
    int r = g - XB_G - WKV_G;
    v = ((const float4*)wproj)[r];
    dst = wpj; di = (size_t)r;
  } else {
    return;
  }
  uint2 o;
  o.x = (u32)f2bf(v.x) | ((u32)f2bf(v.y) << 16);
  o.y = (u32)f2bf(v.z) | ((u32)f2bf(v.w) << 16);
  ((uint2*)dst)[di] = o;
}

// ---------------------------------------------------------------------------
// gemm_bt: C[m,n] = sum_k A[m,k]*W[n,k]; 128x128 tile, BK=32, m97-style.
// MODE 0: store bf16 to Cbf (ldc cols).  MODE 1: +bias, fp32 scatter to [N,B,D].
// ---------------------------------------------------------------------------
template <int MODE>
__global__ __launch_bounds__(256) void gemm_bt(const u16* __restrict__ A,
                                               const u16* __restrict__ W,
                                               u16* __restrict__ Cbf,
                                               float* __restrict__ Cf,
                                               const float* __restrict__ bias,
                                               int ldc) {
  __shared__ u16 sA[128 * 32];
  __shared__ u16 sW[128 * 32];
  const int tid = threadIdx.x;
  const int w = tid >> 6, lane = tid & 63;
  const int m0 = blockIdx.y << 7, n0 = blockIdx.x << 7;
  const int wm = w & 1, wn = w >> 1;
  const int lc = lane & 15, lr = lane >> 4;

  f32x4 zero4 = {0.f, 0.f, 0.f, 0.f};
  f32x4 acc[4][4];
#pragma unroll
  for (int i = 0; i < 4; ++i)
#pragma unroll
    for (int j = 0; j < 4; ++j) acc[i][j] = zero4;

  const int lin0 = (w << 11) + (lane << 4);  // bytes
  const int r0 = lin0 >> 6;
  const int koff = (lane & 3) << 3;
  const u16* gA0 = A + (size_t)(m0 + r0) * DD + koff;
  const u16* gA1 = gA0 + (size_t)16 * DD;
  const u16* gW0 = W + (size_t)(n0 + r0) * DD + koff;
  const u16* gW1 = gW0 + (size_t)16 * DD;
  char* lA0 = (char*)sA + lin0;
  char* lW0 = (char*)sW + lin0;

#pragma unroll 1
  for (int kt = 0; kt < 24; ++kt) {
    __syncthreads();
    gl2lds16(gA0 + kt * 32, lA0);
    gl2lds16(gA1 + kt * 32, lA0 + 1024);
    gl2lds16(gW0 + kt * 32, lW0);
    gl2lds16(gW1 + kt * 32, lW0 + 1024);
    __syncthreads();
    short8 af[4], wf[4];
#pragma unroll
    for (int mt = 0; mt < 4; ++mt)
      af[mt] = *(const short8*)((char*)sA + ((wm << 6) + (mt << 4) + lc) * 64 + (lr << 4));
#pragma unroll
    for (int nt = 0; nt < 4; ++nt)
      wf[nt] = *(const short8*)((char*)sW + ((wn << 6) + (nt << 4) + lc) * 64 + (lr << 4));
#pragma unroll
    for (int mt = 0; mt < 4; ++mt)
#pragma unroll
      for (int nt = 0; nt < 4; ++nt)
        acc[mt][nt] = __builtin_amdgcn_mfma_f32_16x16x32_bf16(af[mt], wf[nt], acc[mt][nt], 0, 0, 0);
  }

  if (MODE == 0) {
#pragma unroll
    for (int mt = 0; mt < 4; ++mt)
#pragma unroll
      for (int r = 0; r < 4; ++r) {
        int m = m0 + (wm << 6) + (mt << 4) + (lr << 2) + r;
        if (m < MROWS) {
          size_t base = (size_t)m * ldc + n0 + (wn << 6) + lc;
#pragma unroll
          for (int nt = 0; nt < 4; ++nt) Cbf[base + (nt << 4)] = f2bf(acc[mt][nt][r]);
        }
      }
  } else {
    float b4[4];
#pragma unroll
    for (int nt = 0; nt < 4; ++nt) b4[nt] = bias[n0 + (wn << 6) + (nt << 4) + lc];
#pragma unroll
    for (int mt = 0; mt < 4; ++mt)
#pragma unroll
      for (int r = 0; r < 4; ++r) {
        int m = m0 + (wm << 6) + (mt << 4) + (lr << 2) + r;
        if (m < MROWS) {
          int bb = m / NSEQ;
          int ns = m - bb * NSEQ;
          float* o = Cf + (size_t)ns * (BB * DD) + bb * DD + n0 + (wn << 6) + lc;
#pragma unroll
          for (int nt = 0; nt < 4; ++nt) o[nt << 4] = acc[mt][nt][r] + b4[nt];
        }
      }
  }
}

// ---------------------------------------------------------------------------
// q0: fp32 q row 0 per batch: q0[b,d'] = sum_e x[0,b,e]*w_qkv[d',e], d' in [0,768)
// ---------------------------------------------------------------------------
__global__ __launch_bounds__(256) void q0_kernel(const float* __restrict__ x,
                                                 const float* __restrict__ wq,
                                                 float* __restrict__ q0) {
  __shared__ float red[256];
  int bid = blockIdx.x;
  int b = bid / HH, c = bid - b * HH;
  int tid = threadIdx.x;
  int dp = (c << 6) + (tid >> 2), part = tid & 3;
  const float4* x4 = (const float4*)(x + (size_t)b * DD + part * 192);
  const float4* w4 = (const float4*)(wq + (size_t)dp * DD + part * 192);
  float acc = 0.f;
#pragma unroll 4
  for (int e = 0; e < 48; ++e) {
    float4 a = x4[e], w = w4[e];
    acc += a.x * w.x + a.y * w.y + a.z * w.z + a.w * w.w;
  }
  red[tid] = acc;
  __syncthreads();
  if (part == 0) q0[b * DD + dp] = red[tid] + red[tid + 1] + red[tid + 2] + red[tid + 3];
}

// ---------------------------------------------------------------------------
// transpose_v: vT[bh][d][key] raw (KPAD cols, zero-padded) AND
//              vn[bh][key][64] = v/max(||v||,eps) bf16 (zero pad rows)
// ---------------------------------------------------------------------------
__global__ __launch_bounds__(256) void transpose_v(const u16* __restrict__ kv,
                                                   u16* __restrict__ vT,
                                                   u16* __restrict__ vn) {
  __shared__ u16 tile[64][72];
  __shared__ float red[256];
  __shared__ float sInv[64];
  int bid = blockIdx.x;
  int kc = bid % 17;
  int t2 = bid / 17;
  int h = t2 % HH, b = t2 / HH;
  int tid = threadIdx.x;
  int kl = tid >> 2, dc = (tid & 3) << 4;
  int key = kc * 64 + kl;
  u32 vals[8];
  if (key < NSEQ) {
    const u32* g = (const u32*)(kv + ((size_t)b * NSEQ + key) * 1536 + DD + h * 64 + dc);
#pragma unroll
    for (int i = 0; i < 8; ++i) vals[i] = g[i];
  } else {
#pragma unroll
    for (int i = 0; i < 8; ++i) vals[i] = 0;
  }
  float part = 0.f;
#pragma unroll
  for (int i = 0; i < 8; ++i) {
    float a = bf2f((u16)(vals[i] & 0xFFFF));
    float c = bf2f((u16)(vals[i] >> 16));
    part += a * a + c * c;
    ((u32*)&tile[kl][dc])[i] = vals[i];
  }
  red[tid] = part;
  __syncthreads();
  if ((tid & 3) == 0) {
    float s = red[tid] + red[tid + 1] + red[tid + 2] + red[tid + 3];
    sInv[kl] = (key < NSEQ) ? 1.0f / fmaxf(sqrtf(s), 1e-6f) : 0.0f;
  }
  __syncthreads();
  // normalized bf16 rows -> vn
  float iv = sInv[kl];
  u32 ovn[8];
#pragma unroll
  for (int i = 0; i < 8; ++i) {
    float a = bf2f((u16)(vals[i] & 0xFFFF)) * iv;
    float c = bf2f((u16)(vals[i] >> 16)) * iv;
    ovn[i] = (u32)f2bf(a) | ((u32)f2bf(c) << 16);
  }
  u32* on = (u32*)(vn + ((size_t)(b * HH + h) * KPAD + key) * 64 + dc);
#pragma unroll
  for (int i = 0; i < 8; ++i) on[i] = ovn[i];
  // raw transpose -> vT
  int dl = tid >> 2, ks = (tid & 3) << 4;
  u32 ov[8];
#pragma unroll
  for (int i = 0; i < 8; ++i)
    ov[i] = (u32)tile[ks + 2 * i][dl] | ((u32)tile[ks + 2 * i + 1][dl] << 16);
  u16* o = vT + (size_t)(b * HH + h) * 64 * KPAD + (size_t)dl * KPAD + kc * 64 + ks;
#pragma unroll
  for (int i = 0; i < 8; ++i) ((u32*)o)[i] = ov[i];
}

// ---------------------------------------------------------------------------
// row0_attn: fp32 scores softmax(q0·k*0.125) @ v  -> attn row 0 per (b,h).
// PV phase: keys split 32 ways x dims 8 ways -> 32 independent 16B loads per
// thread (MLP), LDS reduce. (Old version: 256 serial scalar loads = 73 us.)
// ---------------------------------------------------------------------------
__global__ __launch_bounds__(256) void row0_attn(const float* __restrict__ q0,
                                                 const u16* __restrict__ kv,
                                                 u16* __restrict__ attn) {
  __shared__ float sq[64];
  __shared__ float sc[NSEQ];
  __shared__ float red[256];
  __shared__ float rpv[32][68];  // [key-part][dim], +4 pad breaks bank alias
  int bid = blockIdx.x;
  int b = bid / HH, h = bid - b * HH;
  int tid = threadIdx.x;
  if (tid < 64) sq[tid] = q0[b * DD + h * 64 + tid];
  __syncthreads();
  float mx = -1e30f;
  for (int n = tid; n < NSEQ; n += 256) {
    const u32* kr = (const u32*)(kv + ((size_t)b * NSEQ + n) * 1536 + h * 64);
    float s = 0.f;
#pragma unroll
    for (int i = 0; i < 32; ++i) {
      u32 u = kr[i];
      s += bf2f((u16)(u & 0xFFFF)) * sq[2 * i] + bf2f((u16)(u >> 16)) * sq[2 * i + 1];
    }
    s *= 0.125f;
    sc[n] = s;
    mx = fmaxf(mx, s);
  }
  red[tid] = mx;
  __syncthreads();
  for (int st = 128; st > 0; st >>= 1) {
    if (tid < st) red[tid] = fmaxf(red[tid], red[tid + st]);
    __syncthreads();
  }
  mx = red[0];
  __syncthreads();
  float ds = 0.f;
  for (int n = tid; n < NSEQ; n += 256) {
    float p = __expf(sc[n] - mx);
    sc[n] = p;
    ds += p;
  }
  red[tid] = ds;
  __syncthreads();
  for (int st = 128; st > 0; st >>= 1) {
    if (tid < st) red[tid] += red[tid + st];
    __syncthreads();
  }
  float den = red[0];
  __syncthreads();

  // PV: thread (kp, dc) accumulates dims [dc,dc+8) over keys n = kp + 32j
  int kp = tid >> 3, dc = (tid & 7) << 3;
  const u16* vb = kv + (size_t)b * NSEQ * 1536 + DD + h * 64 + dc;
  float acc[8];
#pragma unroll
  for (int i = 0; i < 8; ++i) acc[i] = 0.f;
#pragma unroll 4
  for (int j = 0; j < 32; ++j) {
    int n = kp + (j << 5);
    uint4 v = *(const uint4*)(vb + (size_t)n * 1536);
    float p = sc[n];
    acc[0] += p * bf2f((u16)(v.x & 0xFFFF));
    acc[1] += p * bf2f((u16)(v.x >> 16));
    acc[2] += p * bf2f((u16)(v.y & 0xFFFF));
    acc[3] += p * bf2f((u16)(v.y >> 16));
    acc[4] += p * bf2f((u16)(v.z & 0xFFFF));
    acc[5] += p * bf2f((u16)(v.z >> 16));
    acc[6] += p * bf2f((u16)(v.w & 0xFFFF));
    acc[7] += p * bf2f((u16)(v.w >> 16));
  }
  if (kp == 0) {  // key 1024
    uint4 v = *(const uint4*)(vb + (size_t)1024 * 1536);
    float p = sc[1024];
    acc[0] += p * bf2f((u16)(v.x & 0xFFFF));
    acc[1] += p * bf2f((u16)(v.x >> 16));
    acc[2] += p * bf2f((u16)(v.y & 0xFFFF));
    acc[3] += p * bf2f((u16)(v.y >> 16));
    acc[4] += p * bf2f((u16)(v.z & 0xFFFF));
    acc[5] += p * bf2f((u16)(v.z >> 16));
    acc[6] += p * bf2f((u16)(v.w & 0xFFFF));
    acc[7] += p * bf2f((u16)(v.w >> 16));
  }
#pragma unroll
  for (int i = 0; i < 8; ++i) rpv[kp][dc + i] = acc[i];
  __syncthreads();
  if (tid < 64) {
    float s = 0.f;
#pragma unroll
    for (int p = 0; p < 32; ++p) s += rpv[p][tid];
    attn[(size_t)b * NSEQ * DD + h * 64 + tid] = f2bf(s / den);
  }
}

// ---------------------------------------------------------------------------
// vv_attn: per (b,h,128-q-tile): S^T = Kn·Qn^T (MFMA, pre-normalized bf16),
// p = exp2(s*0.125*log2e)  (single literal mul + v_exp + v_perm pack),
// P->LDS (b64, [q][k]), out += P@V^T (MFMA), den += P@ones (MFMA).
// No online max needed: |s| <= 0.125. Pad keys masked only in last K-tile.
// ---------------------------------------------------------------------------
__global__ __launch_bounds__(256) void vv_attn(const u16* __restrict__ vn,
                                               const u16* __restrict__ vT,
                                               u16* __restrict__ attn) {
  __shared__ u16 sQ[2 * 128 * 32];  // [d-half][qrow 128][k 32]
  __shared__ u16 sK[2 * 64 * 32];   // [d-half][keyrow 64][k 32]
  __shared__ u16 sV[2 * 64 * 32];   // [key-half][d 64][k 32]  (from vT)
  __shared__ u16 sP[128 * 72];      // [q][key 64 (+8 pad)], 144B row stride

  const int tid = threadIdx.x, w = tid >> 6, lane = tid & 63;
  const int lc = lane & 15, lr = lane >> 4;
  const int mb = blockIdx.x, h = blockIdx.y, b = blockIdx.z;
  const int bh = b * HH + h;
  const int m0 = mb << 7;
  const char* nb = (const char*)(vn + (size_t)bh * KPAD * 64);  // 128B rows
  const char* tb = (const char*)(vT + (size_t)bh * 64 * KPAD);  // 2176B rows

  // stage Q tile (vn rows 1+m0 .. 1+m0+127), once; LDS layout [hf][row][32]
#pragma unroll
  for (int j = 0; j < 4; ++j) {
    int lin = (w << 12) + (j << 10) + (lane << 4);
    int hf = lin >> 13, r = (lin >> 6) & 127, off = lin & 63;
    gl2lds16(nb + (size_t)(1 + m0 + r) * 128 + hf * 64 + off, (char*)sQ + lin);
  }

  f32x4 zero4 = {0.f, 0.f, 0.f, 0.f};
  f32x4 oacc[2][4];
  f32x4 dacc[2];
#pragma unroll
  for (int i = 0; i < 2; ++i) {
    dacc[i] = zero4;
#pragma unroll
    for (int j = 0; j < 4; ++j) oacc[i][j] = zero4;
  }
  short8 ones;
#pragma unroll
  for (int i = 0; i < 8; ++i) ones[i] = (short)0x3F80;  // bf16 1.0

  const float CEXP = 0.1803368801111204f;  // 0.125 * log2(e)

#pragma unroll 1
  for (int kt = 0; kt < 17; ++kt) {
    __syncthreads();
#pragma unroll
    for (int j = 0; j < 2; ++j) {
      int lin = (w << 11) + (j << 10) + (lane << 4);
      int hf = lin >> 12, r = (lin >> 6) & 63, off = lin & 63;
      gl2lds16(nb + (size_t)(kt * 64 + r) * 128 + hf * 64 + off, (char*)sK + lin);
      gl2lds16(tb + (size_t)r * (KPAD * 2) + kt * 128 + hf * 64 + off, (char*)sV + lin);
    }
    __syncthreads();

    // S^T = Kn_tile @ Qn^T  (C rows = keys, cols = queries) — already cosine
    f32x4 sacc[4][2];
#pragma unroll
    for (int mt = 0; mt < 4; ++mt)
#pragma unroll
      for (int nt = 0; nt < 2; ++nt) sacc[mt][nt] = zero4;
#pragma unroll
    for (int kk = 0; kk < 2; ++kk) {
      short8 ak[4], bq[2];
#pragma unroll
      for (int mt = 0; mt < 4; ++mt)
        ak[mt] = *(const short8*)((char*)sK + (kk << 12) + ((mt << 4) + lc) * 64 + (lr << 4));
#pragma unroll
      for (int nt = 0; nt < 2; ++nt)
        bq[nt] = *(const short8*)((char*)sQ + (kk << 13) + ((w << 5) + (nt << 4) + lc) * 64 + (lr << 4));
#pragma unroll
      for (int mt = 0; mt < 4; ++mt)
#pragma unroll
        for (int nt = 0; nt < 2; ++nt)
          sacc[mt][nt] = __builtin_amdgcn_mfma_f32_16x16x32_bf16(ak[mt], bq[nt], sacc[mt][nt], 0, 0, 0);
    }

    // p = exp2(s * CEXP); round-half-up to bf16 via +0x8000 + v_perm pack;
    // 4 k-consecutive bf16 per lane (b64) into sP[q][k]
#pragma unroll
    for (int mt = 0; mt < 4; ++mt) {
      int kl0 = (mt << 4) + (lr << 2);
#pragma unroll
      for (int nt = 0; nt < 2; ++nt) {
        int q = (w << 5) + (nt << 4) + lc;
        u32 a0 = __float_as_uint(__builtin_amdgcn_exp2f(sacc[mt][nt][0] * CEXP)) + 0x8000u;
        u32 a1 = __float_as_uint(__builtin_amdgcn_exp2f(sacc[mt][nt][1] * CEXP)) + 0x8000u;
        u32 a2 = __float_as_uint(__builtin_amdgcn_exp2f(sacc[mt][nt][2] * CEXP)) + 0x8000u;
        u32 a3 = __float_as_uint(__builtin_amdgcn_exp2f(sacc[mt][nt][3] * CEXP)) + 0x8000u;
        uint2 pv;
        pv.x = __builtin_amdgcn_perm(a1, a0, 0x07060302u);
        pv.y = __builtin_amdgcn_perm(a3, a2, 0x07060302u);
        if (kt == 16) {  // keys 1024..1087: only key 1024 (kl0==0, elem 0) valid
          pv.x = (kl0 == 0) ? (pv.x & 0xFFFFu) : 0u;
          pv.y = 0u;
        }
        *(uint2*)((char*)sP + q * 144 + (kl0 << 1)) = pv;
      }
    }

    // out += P @ V^T ; den += P @ ones   (sP rows are wave-private: no barrier)
#pragma unroll
    for (int kk = 0; kk < 2; ++kk) {
      short8 ap[2], bv[4];
#pragma unroll
      for (int mt = 0; mt < 2; ++mt)
        ap[mt] = *(const short8*)((char*)sP + ((w << 5) + (mt << 4) + lc) * 144 + (kk << 6) + (lr << 4));
#pragma unroll
      for (int nt = 0; nt < 4; ++nt)
        bv[nt] = *(const short8*)((char*)sV + (kk << 12) + ((nt << 4) + lc) * 64 + (lr << 4));
#pragma unroll
      for (int mt = 0; mt < 2; ++mt) {
#pragma unroll
        for (int nt = 0; nt < 4; ++nt)
          oacc[mt][nt] = __builtin_amdgcn_mfma_f32_16x16x32_bf16(ap[mt], bv[nt], oacc[mt][nt], 0, 0, 0);
        dacc[mt] = __builtin_amdgcn_mfma_f32_16x16x32_bf16(ap[mt], ones, dacc[mt], 0, 0, 0);
      }
    }
  }

  // epilogue: out/den -> attn rows 1+m0+q
#pragma unroll
  for (int mt = 0; mt < 2; ++mt) {
#pragma unroll
    for (int r = 0; r < 4; ++r) {
      int q = (w << 5) + (mt << 4) + (lr << 2) + r;
      int nseq = 1 + m0 + q;
      float rdn = 1.0f / dacc[mt][r];
      size_t obase = ((size_t)b * NSEQ + nseq) * DD + h * 64 + lc;
#pragma unroll
      for (int nt = 0; nt < 4; ++nt) attn[obase + (nt << 4)] = f2bf(oacc[mt][nt][r] * rdn);
    }
  }
}

// ---------------------------------------------------------------------------
// launcher
// ---------------------------------------------------------------------------
extern "C" void kernel_launch(void* const* d_in, const int* in_sizes, int n_in,
                              void* d_out, int out_size, void* d_ws, size_t ws_size,
                              hipStream_t stream) {
  const float* x      = (const float*)d_in[0];
  const float* w_qkv  = (const float*)d_in[1];
  const float* w_proj = (const float*)d_in[2];
  const float* b_proj = (const float*)d_in[3];
  float* out = (float*)d_out;
  char* ws = (char*)d_ws;

  // workspace layout (bytes). xb region is reused by vT after the qkv GEMM.
  u16*   xb   = (u16*)(ws + 0);            // 8320*768*2   = 12,779,520
  u16*   vT   = (u16*)(ws + 0);            // 96*64*1088*2 = 13,369,344 (reuses xb, done)
  u16*   wkv  = (u16*)(ws + 13369344);     // 1536*768*2   =  2,359,296
  u16*   wpj  = (u16*)(ws + 15728640);     // 768*768*2    =  1,179,648
  u16*   kvb  = (u16*)(ws + 16908288);     // 8320*1536*2  = 25,559,040
  float* q0   = (float*)(ws + 42467328);   // 8*768*4      =     24,576
  u16*   attn = (u16*)(ws + 42491904);     // 8320*768*2   = 12,779,520
  u16*   vn   = (u16*)(ws + 55271424);     // 96*1088*64*2 = 13,369,344
  // total: 68,640,768 bytes

  prep<<<7968, 256, 0, stream>>>(x, w_qkv, w_proj, xb, wkv, wpj);
  gemm_bt<0><<<dim3(12, 65), 256, 0, stream>>>(xb, wkv, kvb, nullptr, nullptr, 1536);
  q0_kernel<<<96, 256, 0, stream>>>(x, w_qkv, q0);
  transpose_v<<<1632, 256, 0, stream>>>(kvb, vT, vn);     // overwrites xb/wkv region
  row0_attn<<<96, 256, 0, stream>>>(q0, kvb, attn);
  vv_attn<<<dim3(8, 12, 8), 256, 0, stream>>>(vn, vT, attn);
  gemm_bt<1><<<dim3(6, 65), 256, 0, stream>>>(attn, wpj, nullptr, out, b_proj, 768);
}

// Round 4
// 221.839 us; speedup vs baseline: 1.4133x; 1.0687x over previous
//
#include <hip/hip_runtime.h>

typedef unsigned short u16;
typedef unsigned int   u32;
typedef __attribute__((ext_vector_type(8))) short short8;
typedef __attribute__((ext_vector_type(4))) float f32x4;

#define AS1 __attribute__((address_space(1)))
#define AS3 __attribute__((address_space(3)))

#define NSEQ  1025
#define BB    8
#define DD    768
#define HH    12
#define MROWS 8200   // B*N valid rows
#define MPAD  8320   // padded to 65*128
#define KPAD  1088   // keys padded to 17*64

__device__ __forceinline__ void gl2lds16(const void* g, void* l) {
  __builtin_amdgcn_global_load_lds((const AS1 u32*)g, (AS3 u32*)l, 16, 0, 0);
}
__device__ __forceinline__ u16 f2bf(float f) {
  u32 u = __float_as_uint(f);
  return (u16)((u + 0x7FFFu + ((u >> 16) & 1u)) >> 16);
}
__device__ __forceinline__ float bf2f(u16 u) { return __uint_as_float(((u32)u) << 16); }

// ---------------------------------------------------------------------------
// prep: cast x -> xb bf16 [MPAD x 768] (transposed (n,b)->(b,n), pad rows = 0),
//       w_qkv rows [768,2304) -> wkv bf16 [1536 x 768],
//       w_proj -> wpj bf16 [768 x 768]
// ---------------------------------------------------------------------------
__global__ __launch_bounds__(256) void prep(const float* __restrict__ x,
                                            const float* __restrict__ wqkv,
                                            const float* __restrict__ wproj,
                                            u16* __restrict__ xb,
                                            u16* __restrict__ wkv,
                                            u16* __restrict__ wpj) {
  const int XB_G  = MPAD * 192;   // float4 groups
  const int WKV_G = 1536 * 192;
  const int WPJ_G = 768 * 192;
  int g = blockIdx.x * 256 + threadIdx.x;
  float4 v;
  u16* dst;
  size_t di;
  if (g < XB_G) {
    int m = g / 192, e4 = g - m * 192;
    if (m < MROWS) {
      int bb = m / NSEQ, ns = m - bb * NSEQ;
      v = ((const float4*)x)[(size_t)(ns * BB + bb) * 192 + e4];
    } else {
      v.x = v.y = v.z = v.w = 0.f;
    }
    dst = xb; di = (size_t)g;
  } else if (g < XB_G + WKV_G) {
    int r = g - XB_G;
    v = ((const float4*)wqkv)[(size_t)147456 + r];  // skip first 768 rows
    dst = wkv; di = (size_t)r;
  } else if (g < XB_G + WKV_G + WPJ_G) {
    int r = g - XB_G - WKV_G;
    v = ((const float4*)wproj)[r];
    dst = wpj; di = (size_t)r;
  } else {
    return;
  }
  uint2 o;
  o.x = (u32)f2bf(v.x) | ((u32)f2bf(v.y) << 16);
  o.y = (u32)f2bf(v.z) | ((u32)f2bf(v.w) << 16);
  ((uint2*)dst)[di] = o;
}

// ---------------------------------------------------------------------------
// gemm_bt: C[m,n] = sum_k A[m,k]*W[n,k]; 128x128 tile, BK=64 (12 iters of 32
// MFMA -> half the barrier drains vs BK=32). XCD-aware 1D grid: id&7 owns
// m-tiles {r, r+8, ...} so same-XCD blocks share A-tiles; W stays L2-resident.
// NT = n-tiles. MODE 0: bf16 store. MODE 1: +bias, fp32 scatter to [N,B,D].
// ---------------------------------------------------------------------------
template <int MODE, int NT>
__global__ __launch_bounds__(256) void gemm_bt(const u16* __restrict__ A,
                                               const u16* __restrict__ W,
                                               u16* __restrict__ Cbf,
                                               float* __restrict__ Cf,
                                               const float* __restrict__ bias,
                                               int ldc) {
  __shared__ u16 sA[128 * 64];
  __shared__ u16 sW[128 * 64];
  const int id = blockIdx.x;
  const int rx = id & 7, qx = id >> 3;
  const int kq = qx / NT;
  const int m_t = rx + (kq << 3);
  if (m_t > 64) return;
  const int n_t = qx - kq * NT;
  const int m0 = m_t << 7, n0 = n_t << 7;

  const int tid = threadIdx.x;
  const int w = tid >> 6, lane = tid & 63;
  const int wm = w & 1, wn = w >> 1;
  const int lc = lane & 15, lr = lane >> 4;

  f32x4 zero4 = {0.f, 0.f, 0.f, 0.f};
  f32x4 acc[4][4];
#pragma unroll
  for (int i = 0; i < 4; ++i)
#pragma unroll
    for (int j = 0; j < 4; ++j) acc[i][j] = zero4;

  const int r0 = tid >> 3;        // staging row 0..31 (+32 per chunk j)
  const int ko = (tid & 7) << 3;  // k-offset in elements
  const u16* gA = A + (size_t)(m0 + r0) * DD + ko;
  const u16* gW = W + (size_t)(n0 + r0) * DD + ko;
  char* lA = (char*)sA + tid * 16;
  char* lW = (char*)sW + tid * 16;

#pragma unroll 1
  for (int kt = 0; kt < 12; ++kt) {
    __syncthreads();
#pragma unroll
    for (int j = 0; j < 4; ++j) {
      gl2lds16(gA + (size_t)j * 32 * DD + kt * 64, lA + j * 4096);
      gl2lds16(gW + (size_t)j * 32 * DD + kt * 64, lW + j * 4096);
    }
    __syncthreads();
#pragma unroll
    for (int kk = 0; kk < 2; ++kk) {
      short8 af[4], wf[4];
#pragma unroll
      for (int mt = 0; mt < 4; ++mt)
        af[mt] = *(const short8*)((char*)sA + ((wm << 6) + (mt << 4) + lc) * 128 + (kk << 6) + (lr << 4));
#pragma unroll
      for (int nt = 0; nt < 4; ++nt)
        wf[nt] = *(const short8*)((char*)sW + ((wn << 6) + (nt << 4) + lc) * 128 + (kk << 6) + (lr << 4));
#pragma unroll
      for (int mt = 0; mt < 4; ++mt)
#pragma unroll
        for (int nt = 0; nt < 4; ++nt)
          acc[mt][nt] = __builtin_amdgcn_mfma_f32_16x16x32_bf16(af[mt], wf[nt], acc[mt][nt], 0, 0, 0);
    }
  }

  if (MODE == 0) {
#pragma unroll
    for (int mt = 0; mt < 4; ++mt)
#pragma unroll
      for (int r = 0; r < 4; ++r) {
        int m = m0 + (wm << 6) + (mt << 4) + (lr << 2) + r;
        if (m < MROWS) {
          size_t base = (size_t)m * ldc + n0 + (wn << 6) + lc;
#pragma unroll
          for (int nt = 0; nt < 4; ++nt) Cbf[base + (nt << 4)] = f2bf(acc[mt][nt][r]);
        }
      }
  } else {
    float b4[4];
#pragma unroll
    for (int nt = 0; nt < 4; ++nt) b4[nt] = bias[n0 + (wn << 6) + (nt << 4) + lc];
#pragma unroll
    for (int mt = 0; mt < 4; ++mt)
#pragma unroll
      for (int r = 0; r < 4; ++r) {
        int m = m0 + (wm << 6) + (mt << 4) + (lr << 2) + r;
        if (m < MROWS) {
          int bb = m / NSEQ;
          int ns = m - bb * NSEQ;
          float* o = Cf + (size_t)ns * (BB * DD) + bb * DD + n0 + (wn << 6) + lc;
#pragma unroll
          for (int nt = 0; nt < 4; ++nt) o[nt << 4] = acc[mt][nt][r] + b4[nt];
        }
      }
  }
}

// ---------------------------------------------------------------------------
// q0: fp32 q row 0 per batch: q0[b,d'] = sum_e x[0,b,e]*w_qkv[d',e], d' in [0,768)
// ---------------------------------------------------------------------------
__global__ __launch_bounds__(256) void q0_kernel(const float* __restrict__ x,
                                                 const float* __restrict__ wq,
                                                 float* __restrict__ q0) {
  __shared__ float red[256];
  int bid = blockIdx.x;
  int b = bid / HH, c = bid - b * HH;
  int tid = threadIdx.x;
  int dp = (c << 6) + (tid >> 2), part = tid & 3;
  const float4* x4 = (const float4*)(x + (size_t)b * DD + part * 192);
  const float4* w4 = (const float4*)(wq + (size_t)dp * DD + part * 192);
  float acc = 0.f;
#pragma unroll 4
  for (int e = 0; e < 48; ++e) {
    float4 a = x4[e], w = w4[e];
    acc += a.x * w.x + a.y * w.y + a.z * w.z + a.w * w.w;
  }
  red[tid] = acc;
  __syncthreads();
  if (part == 0) q0[b * DD + dp] = red[tid] + red[tid + 1] + red[tid + 2] + red[tid + 3];
}

// ---------------------------------------------------------------------------
// transpose_v: vT[bh][d][key] raw (KPAD cols, zero-padded) AND
//              vn[bh][key][64] = v/max(||v||,eps) bf16 (zero pad rows)
// ---------------------------------------------------------------------------
__global__ __launch_bounds__(256) void transpose_v(const u16* __restrict__ kv,
                                                   u16* __restrict__ vT,
                                                   u16* __restrict__ vn) {
  __shared__ u16 tile[64][72];
  __shared__ float red[256];
  __shared__ float sInv[64];
  int bid = blockIdx.x;
  int kc = bid % 17;
  int t2 = bid / 17;
  int h = t2 % HH, b = t2 / HH;
  int tid = threadIdx.x;
  int kl = tid >> 2, dc = (tid & 3) << 4;
  int key = kc * 64 + kl;
  u32 vals[8];
  if (key < NSEQ) {
    const u32* g = (const u32*)(kv + ((size_t)b * NSEQ + key) * 1536 + DD + h * 64 + dc);
#pragma unroll
    for (int i = 0; i < 8; ++i) vals[i] = g[i];
  } else {
#pragma unroll
    for (int i = 0; i < 8; ++i) vals[i] = 0;
  }
  float part = 0.f;
#pragma unroll
  for (int i = 0; i < 8; ++i) {
    float a = bf2f((u16)(vals[i] & 0xFFFF));
    float c = bf2f((u16)(vals[i] >> 16));
    part += a * a + c * c;
    ((u32*)&tile[kl][dc])[i] = vals[i];
  }
  red[tid] = part;
  __syncthreads();
  if ((tid & 3) == 0) {
    float s = red[tid] + red[tid + 1] + red[tid + 2] + red[tid + 3];
    sInv[kl] = (key < NSEQ) ? 1.0f / fmaxf(sqrtf(s), 1e-6f) : 0.0f;
  }
  __syncthreads();
  // normalized bf16 rows -> vn
  float iv = sInv[kl];
  u32 ovn[8];
#pragma unroll
  for (int i = 0; i < 8; ++i) {
    float a = bf2f((u16)(vals[i] & 0xFFFF)) * iv;
    float c = bf2f((u16)(vals[i] >> 16)) * iv;
    ovn[i] = (u32)f2bf(a) | ((u32)f2bf(c) << 16);
  }
  u32* on = (u32*)(vn + ((size_t)(b * HH + h) * KPAD + key) * 64 + dc);
#pragma unroll
  for (int i = 0; i < 8; ++i) on[i] = ovn[i];
  // raw transpose -> vT
  int dl = tid >> 2, ks = (tid & 3) << 4;
  u32 ov[8];
#pragma unroll
  for (int i = 0; i < 8; ++i)
    ov[i] = (u32)tile[ks + 2 * i][dl] | ((u32)tile[ks + 2 * i + 1][dl] << 16);
  u16* o = vT + (size_t)(b * HH + h) * 64 * KPAD + (size_t)dl * KPAD + kc * 64 + ks;
#pragma unroll
  for (int i = 0; i < 8; ++i) ((u32*)o)[i] = ov[i];
}

// ---------------------------------------------------------------------------
// row0_attn: fp32 scores softmax(q0·k*0.125) @ v  -> attn row 0 per (b,h).
// PV phase: keys split 32 ways x dims 8 ways -> 32 independent 16B loads per
// thread (MLP), LDS reduce.
// ---------------------------------------------------------------------------
__global__ __launch_bounds__(256) void row0_attn(const float* __restrict__ q0,
                                                 const u16* __restrict__ kv,
                                                 u16* __restrict__ attn) {
  __shared__ float sq[64];
  __shared__ float sc[NSEQ];
  __shared__ float red[256];
  __shared__ float rpv[32][68];  // [key-part][dim], +4 pad breaks bank alias
  int bid = blockIdx.x;
  int b = bid / HH, h = bid - b * HH;
  int tid = threadIdx.x;
  if (tid < 64) sq[tid] = q0[b * DD + h * 64 + tid];
  __syncthreads();
  float mx = -1e30f;
  for (int n = tid; n < NSEQ; n += 256) {
    const u32* kr = (const u32*)(kv + ((size_t)b * NSEQ + n) * 1536 + h * 64);
    float s = 0.f;
#pragma unroll
    for (int i = 0; i < 32; ++i) {
      u32 u = kr[i];
      s += bf2f((u16)(u & 0xFFFF)) * sq[2 * i] + bf2f((u16)(u >> 16)) * sq[2 * i + 1];
    }
    s *= 0.125f;
    sc[n] = s;
    mx = fmaxf(mx, s);
  }
  red[tid] = mx;
  __syncthreads();
  for (int st = 128; st > 0; st >>= 1) {
    if (tid < st) red[tid] = fmaxf(red[tid], red[tid + st]);
    __syncthreads();
  }
  mx = red[0];
  __syncthreads();
  float ds = 0.f;
  for (int n = tid; n < NSEQ; n += 256) {
    float p = __expf(sc[n] - mx);
    sc[n] = p;
    ds += p;
  }
  red[tid] = ds;
  __syncthreads();
  for (int st = 128; st > 0; st >>= 1) {
    if (tid < st) red[tid] += red[tid + st];
    __syncthreads();
  }
  float den = red[0];
  __syncthreads();

  // PV: thread (kp, dc) accumulates dims [dc,dc+8) over keys n = kp + 32j
  int kp = tid >> 3, dc = (tid & 7) << 3;
  const u16* vb = kv + (size_t)b * NSEQ * 1536 + DD + h * 64 + dc;
  float acc[8];
#pragma unroll
  for (int i = 0; i < 8; ++i) acc[i] = 0.f;
#pragma unroll 4
  for (int j = 0; j < 32; ++j) {
    int n = kp + (j << 5);
    uint4 v = *(const uint4*)(vb + (size_t)n * 1536);
    float p = sc[n];
    acc[0] += p * bf2f((u16)(v.x & 0xFFFF));
    acc[1] += p * bf2f((u16)(v.x >> 16));
    acc[2] += p * bf2f((u16)(v.y & 0xFFFF));
    acc[3] += p * bf2f((u16)(v.y >> 16));
    acc[4] += p * bf2f((u16)(v.z & 0xFFFF));
    acc[5] += p * bf2f((u16)(v.z >> 16));
    acc[6] += p * bf2f((u16)(v.w & 0xFFFF));
    acc[7] += p * bf2f((u16)(v.w >> 16));
  }
  if (kp == 0) {  // key 1024
    uint4 v = *(const uint4*)(vb + (size_t)1024 * 1536);
    float p = sc[1024];
    acc[0] += p * bf2f((u16)(v.x & 0xFFFF));
    acc[1] += p * bf2f((u16)(v.x >> 16));
    acc[2] += p * bf2f((u16)(v.y & 0xFFFF));
    acc[3] += p * bf2f((u16)(v.y >> 16));
    acc[4] += p * bf2f((u16)(v.z & 0xFFFF));
    acc[5] += p * bf2f((u16)(v.z >> 16));
    acc[6] += p * bf2f((u16)(v.w & 0xFFFF));
    acc[7] += p * bf2f((u16)(v.w >> 16));
  }
#pragma unroll
  for (int i = 0; i < 8; ++i) rpv[kp][dc + i] = acc[i];
  __syncthreads();
  if (tid < 64) {
    float s = 0.f;
#pragma unroll
    for (int p = 0; p < 32; ++p) s += rpv[p][tid];
    attn[(size_t)b * NSEQ * DD + h * 64 + tid] = f2bf(s / den);
  }
}

// ---------------------------------------------------------------------------
// vv_attn: per (bh, 128-q-tile): S^T = Kn·Qn^T (MFMA), p = exp2(s*CEXP),
// P->LDS, out += P@V^T, den += P@ones. Grid (96,8): x=bh, y=q-tile, so the
// 8 q-tiles sharing one bh's K/V have linear-id stride 96 = 0 mod 8 -> same
// XCD -> K/V stays in that XCD's L2 (12 bh x 278 KB = 3.3 MB < 4 MB).
// ---------------------------------------------------------------------------
__global__ __launch_bounds__(256) void vv_attn(const u16* __restrict__ vn,
                                               const u16* __restrict__ vT,
                                               u16* __restrict__ attn) {
  __shared__ u16 sQ[2 * 128 * 32];  // [d-half][qrow 128][k 32]
  __shared__ u16 sK[2 * 64 * 32];   // [d-half][keyrow 64][k 32]
  __shared__ u16 sV[2 * 64 * 32];   // [key-half][d 64][k 32]  (from vT)
  __shared__ u16 sP[128 * 72];      // [q][key 64 (+8 pad)], 144B row stride

  const int tid = threadIdx.x, w = tid >> 6, lane = tid & 63;
  const int lc = lane & 15, lr = lane >> 4;
  const int bh = blockIdx.x;        // 0..95
  const int m0 = blockIdx.y << 7;
  const int b = bh / HH, h = bh - b * HH;
  const char* nb = (const char*)(vn + (size_t)bh * KPAD * 64);  // 128B rows
  const char* tb = (const char*)(vT + (size_t)bh * 64 * KPAD);  // 2176B rows

  // stage Q tile (vn rows 1+m0 .. 1+m0+127), once; LDS layout [hf][row][32]
#pragma unroll
  for (int j = 0; j < 4; ++j) {
    int lin = (w << 12) + (j << 10) + (lane << 4);
    int hf = lin >> 13, r = (lin >> 6) & 127, off = lin & 63;
    gl2lds16(nb + (size_t)(1 + m0 + r) * 128 + hf * 64 + off, (char*)sQ + lin);
  }

  f32x4 zero4 = {0.f, 0.f, 0.f, 0.f};
  f32x4 oacc[2][4];
  f32x4 dacc[2];
#pragma unroll
  for (int i = 0; i < 2; ++i) {
    dacc[i] = zero4;
#pragma unroll
    for (int j = 0; j < 4; ++j) oacc[i][j] = zero4;
  }
  short8 ones;
#pragma unroll
  for (int i = 0; i < 8; ++i) ones[i] = (short)0x3F80;  // bf16 1.0

  const float CEXP = 0.1803368801111204f;  // 0.125 * log2(e)

#pragma unroll 1
  for (int kt = 0; kt < 17; ++kt) {
    __syncthreads();
#pragma unroll
    for (int j = 0; j < 2; ++j) {
      int lin = (w << 11) + (j << 10) + (lane << 4);
      int hf = lin >> 12, r = (lin >> 6) & 63, off = lin & 63;
      gl2lds16(nb + (size_t)(kt * 64 + r) * 128 + hf * 64 + off, (char*)sK + lin);
      gl2lds16(tb + (size_t)r * (KPAD * 2) + kt * 128 + hf * 64 + off, (char*)sV + lin);
    }
    __syncthreads();

    // S^T = Kn_tile @ Qn^T  (C rows = keys, cols = queries) — already cosine
    f32x4 sacc[4][2];
#pragma unroll
    for (int mt = 0; mt < 4; ++mt)
#pragma unroll
      for (int nt = 0; nt < 2; ++nt) sacc[mt][nt] = zero4;
#pragma unroll
    for (int kk = 0; kk < 2; ++kk) {
      short8 ak[4], bq[2];
#pragma unroll
      for (int mt = 0; mt < 4; ++mt)
        ak[mt] = *(const short8*)((char*)sK + (kk << 12) + ((mt << 4) + lc) * 64 + (lr << 4));
#pragma unroll
      for (int nt = 0; nt < 2; ++nt)
        bq[nt] = *(const short8*)((char*)sQ + (kk << 13) + ((w << 5) + (nt << 4) + lc) * 64 + (lr << 4));
#pragma unroll
      for (int mt = 0; mt < 4; ++mt)
#pragma unroll
        for (int nt = 0; nt < 2; ++nt)
          sacc[mt][nt] = __builtin_amdgcn_mfma_f32_16x16x32_bf16(ak[mt], bq[nt], sacc[mt][nt], 0, 0, 0);
    }

    // p = exp2(s * CEXP); round-half-up to bf16 via +0x8000 + v_perm pack;
    // 4 k-consecutive bf16 per lane (b64) into sP[q][k]
#pragma unroll
    for (int mt = 0; mt < 4; ++mt) {
      int kl0 = (mt << 4) + (lr << 2);
#pragma unroll
      for (int nt = 0; nt < 2; ++nt) {
        int q = (w << 5) + (nt << 4) + lc;
        u32 a0 = __float_as_uint(__builtin_amdgcn_exp2f(sacc[mt][nt][0] * CEXP)) + 0x8000u;
        u32 a1 = __float_as_uint(__builtin_amdgcn_exp2f(sacc[mt][nt][1] * CEXP)) + 0x8000u;
        u32 a2 = __float_as_uint(__builtin_amdgcn_exp2f(sacc[mt][nt][2] * CEXP)) + 0x8000u;
        u32 a3 = __float_as_uint(__builtin_amdgcn_exp2f(sacc[mt][nt][3] * CEXP)) + 0x8000u;
        uint2 pv;
        pv.x = __builtin_amdgcn_perm(a1, a0, 0x07060302u);
        pv.y = __builtin_amdgcn_perm(a3, a2, 0x07060302u);
        if (kt == 16) {  // keys 1024..1087: only key 1024 (kl0==0, elem 0) valid
          pv.x = (kl0 == 0) ? (pv.x & 0xFFFFu) : 0u;
          pv.y = 0u;
        }
        *(uint2*)((char*)sP + q * 144 + (kl0 << 1)) = pv;
      }
    }

    // out += P @ V^T ; den += P @ ones   (sP rows are wave-private: no barrier)
#pragma unroll
    for (int kk = 0; kk < 2; ++kk) {
      short8 ap[2], bv[4];
#pragma unroll
      for (int mt = 0; mt < 2; ++mt)
        ap[mt] = *(const short8*)((char*)sP + ((w << 5) + (mt << 4) + lc) * 144 + (kk << 6) + (lr << 4));
#pragma unroll
      for (int nt = 0; nt < 4; ++nt)
        bv[nt] = *(const short8*)((char*)sV + (kk << 12) + ((nt << 4) + lc) * 64 + (lr << 4));
#pragma unroll
      for (int mt = 0; mt < 2; ++mt) {
#pragma unroll
        for (int nt = 0; nt < 4; ++nt)
          oacc[mt][nt] = __builtin_amdgcn_mfma_f32_16x16x32_bf16(ap[mt], bv[nt], oacc[mt][nt], 0, 0, 0);
        dacc[mt] = __builtin_amdgcn_mfma_f32_16x16x32_bf16(ap[mt], ones, dacc[mt], 0, 0, 0);
      }
    }
  }

  // epilogue: out/den -> attn rows 1+m0+q
#pragma unroll
  for (int mt = 0; mt < 2; ++mt) {
#pragma unroll
    for (int r = 0; r < 4; ++r) {
      int q = (w << 5) + (mt << 4) + (lr << 2) + r;
      int nseq = 1 + m0 + q;
      float rdn = 1.0f / dacc[mt][r];
      size_t obase = ((size_t)b * NSEQ + nseq) * DD + h * 64 + lc;
#pragma unroll
      for (int nt = 0; nt < 4; ++nt) attn[obase + (nt << 4)] = f2bf(oacc[mt][nt][r] * rdn);
    }
  }
}

// ---------------------------------------------------------------------------
// launcher
// ---------------------------------------------------------------------------
extern "C" void kernel_launch(void* const* d_in, const int* in_sizes, int n_in,
                              void* d_out, int out_size, void* d_ws, size_t ws_size,
                              hipStream_t stream) {
  const float* x      = (const float*)d_in[0];
  const float* w_qkv  = (const float*)d_in[1];
  const float* w_proj = (const float*)d_in[2];
  const float* b_proj = (const float*)d_in[3];
  float* out = (float*)d_out;
  char* ws = (char*)d_ws;

  // workspace layout (bytes). xb region is reused by vT after the qkv GEMM.
  u16*   xb   = (u16*)(ws + 0);            // 8320*768*2   = 12,779,520
  u16*   vT   = (u16*)(ws + 0);            // 96*64*1088*2 = 13,369,344 (reuses xb, done)
  u16*   wkv  = (u16*)(ws + 13369344);     // 1536*768*2   =  2,359,296
  u16*   wpj  = (u16*)(ws + 15728640);     // 768*768*2    =  1,179,648
  u16*   kvb  = (u16*)(ws + 16908288);     // 8320*1536*2  = 25,559,040
  float* q0   = (float*)(ws + 42467328);   // 8*768*4      =     24,576
  u16*   attn = (u16*)(ws + 42491904);     // 8320*768*2   = 12,779,520
  u16*   vn   = (u16*)(ws + 55271424);     // 96*1088*64*2 = 13,369,344
  // total: 68,640,768 bytes

  prep<<<7968, 256, 0, stream>>>(x, w_qkv, w_proj, xb, wkv, wpj);
  gemm_bt<0, 12><<<864, 256, 0, stream>>>(xb, wkv, kvb, nullptr, nullptr, 1536);
  q0_kernel<<<96, 256, 0, stream>>>(x, w_qkv, q0);
  transpose_v<<<1632, 256, 0, stream>>>(kvb, vT, vn);     // overwrites xb/wkv region
  row0_attn<<<96, 256, 0, stream>>>(q0, kvb, attn);
  vv_attn<<<dim3(96, 8), 256, 0, stream>>>(vn, vT, attn);
  gemm_bt<1, 6><<<432, 256, 0, stream>>>(attn, wpj, nullptr, out, b_proj, 768);
}